// Round 15
// baseline (71.754 us; speedup 1.0000x reference)
//
#include <hip/hip_runtime.h>

// Problem constants (fixed by setup_inputs)
#define BATCH 2
#define NPTS  8192
#define KS    16
#define KNN   8
#define R2LOOSE 0.0101f      // loose prefilter ball; exact radius test at end
#define KEYMASK 0xFFFFE000u  // high 19 bits of d2; low 13 bits = sorted pos
#define NCELL   1000         // 10x10x10 grid, cell size 0.1 (= RADIUS)
#define CSTRIDE 1024         // padded per-batch cell-array stride

// Main kernel geometry (R7/R14 best-measured: 8 queries/wave, 8 sublanes)
#define QB       64                 // queries per block
#define NWAVE    8                  // waves per block (512 threads)
#define NTHREADS 512
#define CAP      32                 // collect capacity per thread
#define SLAB     256                // per-wave staged candidates per chunk
#define NBLK     (BATCH * NPTS / QB)   // 256 blocks

struct __align__(4) pt3 { float x, y, z; };   // 12B contiguous point

__device__ __forceinline__ int cell_of(float x, float y, float z) {
    int cx = (int)(x * 10.0f); cx = cx > 9 ? 9 : cx;
    int cy = (int)(y * 10.0f); cy = cy > 9 ? 9 : cy;
    int cz = (int)(z * 10.0f); cz = cz > 9 ? 9 : cz;
    return (cx * 10 + cy) * 10 + cz;
}

// ---- single build node (R0 structure; R15: point preload as one 12-byte
// dwordx3 per point instead of 3 scalar dword loads -- 3x fewer memory
// instructions on build's front critical path; same bytes, bit-identical) ---
__global__ __launch_bounds__(1024) void build_kernel(
    const float* __restrict__ pc,
    float4* __restrict__ cs, int* __restrict__ sidx,
    int* __restrict__ cstart, float* __restrict__ out)
{
    __shared__ int h[1024];
    __shared__ int wsum[16];
    const int blk = blockIdx.x, t = threadIdx.x;
    const int b = blk >> 3, seg = blk & 7;     // batch, own segment
    const int lane = t & 63, w = t >> 6;

    h[t] = 0;
    if (blk == 0 && t == 0) out[0] = 0.0f;     // runs before main in-stream

    const pt3* p3 = (const pt3*)(pc + (size_t)b * NPTS * 3);
    float X[8], Y[8], Z[8]; int CC[8];
#pragma unroll
    for (int j = 0; j < 8; ++j) {
        const pt3 q = p3[j * 1024 + t];        // 12B/lane, coalesced
        X[j] = q.x; Y[j] = q.y; Z[j] = q.z;
        CC[j] = cell_of(q.x, q.y, q.z);
    }
    __syncthreads();   // h zeroed, all loads issued

    int myold = 0;
#pragma unroll
    for (int j = 0; j < 8; ++j) {              // segment-ordered adds
        const int old = atomicAdd(&h[CC[j]], 1);
        if (j == seg) myold = old;             // bel + intra-seg rank
        __syncthreads();
    }

    const int sum = h[t];
    int inc = sum;
#pragma unroll
    for (int off = 1; off < 64; off <<= 1) {
        const int v = __shfl_up(inc, off);
        if (lane >= off) inc += v;
    }
    if (lane == 63) wsum[w] = inc;
    __syncthreads();
    if (w == 0) {
        const int v = (lane < 16) ? wsum[lane] : 0;
        int iv = v;
#pragma unroll
        for (int off = 1; off < 16; off <<= 1) {
            const int u = __shfl_up(iv, off);
            if (lane >= off) iv += u;
        }
        if (lane < 16) wsum[lane] = iv - v;    // exclusive wave offsets
    }
    __syncthreads();
    const int excl = inc - sum + wsum[w];      // per-batch exclusive prefix
    if (seg == 0) cstart[b * CSTRIDE + t] = excl;   // cells>=1000 -> 8192
    __syncthreads();
    h[t] = excl;                               // per-cell start, reusable
    __syncthreads();

    float mx = X[0], my_ = Y[0], mz = Z[0]; int mc = CC[0];
#pragma unroll
    for (int j = 1; j < 8; ++j)
        if (seg == j) { mx = X[j]; my_ = Y[j]; mz = Z[j]; mc = CC[j]; }

    const int pos = h[mc] + myold;
    const float sq = fmaf(mz, mz, fmaf(my_, my_, mx * mx));
    cs[b * NPTS + pos]   = make_float4(mx, my_, mz, -0.5f * sq);
    sidx[b * NPTS + pos] = seg * 1024 + t;     // orig within-batch index
}

// ---- fused knn + loss (R14-exact: best-measured, 70.77us) ------------------
#define CEX(a, b) { const unsigned mn_ = min(a, b), mx_ = max(a, b); \
                    a = mn_; b = mx_; }

__global__ __launch_bounds__(512) void knn_loss_kernel(
    const float4* __restrict__ cs,     // cell-sorted (x,y,z,-0.5|c|^2)
    const int*    __restrict__ sidx,   // sorted pos -> orig idx
    const int*    __restrict__ cstart, // per-batch cell starts (padded 1024)
    const float*  __restrict__ mask,   // (B, N, KS) in ORIGINAL order
    float* __restrict__ out)
{
    __shared__ float4   stg4[NWAVE][SLAB];     // 32 KB per-wave slabs
    __shared__ int      stgi[NWAVE][SLAB];     //  8 KB their sorted positions
    __shared__ unsigned sbuf[CAP * NTHREADS];  // 64 KB collect buffer
    __shared__ float    red[NWAVE];

    const int t = threadIdx.x;
    const int l = t & 63;
    const int k = l & 7;          // candidate sublane 0..7
    const int s = t >> 6;         // wave id 0..7
    const int su = __builtin_amdgcn_readfirstlane(s);
    const int Q = (t >> 3) & 63;  // query slot 0..63 (= s*8 + qsub)
    const int blk = blockIdx.x;
    const int b  = blk >> 7;
    const int q0 = (blk & 127) * QB;
    const int qpos = q0 + Q;

    const float4* csb = cs + b * NPTS;
    const float4 qc = csb[qpos];
    const int    qi = sidx[b * NPTS + qpos];

    const float qx = qc.x, qy = qc.y, qz = qc.z;
    const float qs = -2.0f * qc.w;                 // exact (power of 2)
    const float negthr = (qs - R2LOOSE) * 0.5f;    // pass iff tt >= negthr
    const unsigned SENT = (__float_as_uint(R2LOOSE) & KEYMASK) | 0x1FFFu;

    // wave's 8-query lex-cell run (8 copies of each query in the wave)
    int lex = cell_of(qx, qy, qz);
    int cmn = lex, cmx = lex;
#pragma unroll
    for (int off = 32; off; off >>= 1) {
        cmn = min(cmn, __shfl_xor(cmn, off));
        cmx = max(cmx, __shfl_xor(cmx, off));
    }
    const int cfirst = __builtin_amdgcn_readfirstlane(cmn);
    const int clast  = __builtin_amdgcn_readfirstlane(cmx);

    // 9 disjoint covering intervals (chained dedup; R7-verified scheme)
    const int* csp = cstart + b * CSTRIDE;
    int P[9], cum[9];
    int run = 0, Cw = 0;
    const int offs[9] = {-110, -100, -90, -10, 0, 10, 90, 100, 110};
#pragma unroll
    for (int i = 0; i < 9; ++i) {
        int lo = cfirst + offs[i] - 1;
        int hp = clast + offs[i] + 2;            // exclusive
        lo = min(max(lo, 0), 1000);
        hp = min(max(hp, 0), 1000);
        lo = max(lo, run);
        hp = max(hp, lo);
        run = hp;
        const int p = csp[lo], e = csp[hp];
        P[i] = p; cum[i] = Cw; Cw += e - p;
    }

    // append-only collect, branchless
    int cnt = 0;
    auto EVAL = [&](const float4& c, int spos) {
        const float tt = fmaf(c.x, qx, fmaf(c.y, qy, fmaf(c.z, qz, c.w)));
        const float d2 = fmaxf(fmaf(-2.0f, tt, qs), 0.0f);
        const unsigned key =
            (__float_as_uint(d2) & KEYMASK) | (unsigned)spos;
        const int slot = cnt < (CAP - 1) ? cnt : (CAP - 1);
        sbuf[slot * NTHREADS + t] = key;
        cnt += (tt >= negthr) ? 1 : 0;
    };

    // chunked per-wave stage + eval (no block barriers; wave-local fence)
    for (int fb = 0; fb < Cw; fb += SLAB) {
        const int n = min(SLAB, Cw - fb);        // wave-uniform
        for (int f = l; f < n; f += 64) {        // 64-wide coalesced stage
            const int g = fb + f;
            int sp = P[0] + g;
#pragma unroll
            for (int i = 1; i < 9; ++i)
                sp = (g >= cum[i]) ? P[i] + (g - cum[i]) : sp;
            stg4[su][f] = csb[sp];
            stgi[su][f] = sp;
        }
        asm volatile("s_waitcnt lgkmcnt(0)" ::: "memory");  // stage visible

        for (int j = k; j < n; j += 8) {         // sublane-strided eval
            const float4 c = stg4[su][j];
            const int   sp = stgi[su][j];
            EVAL(c, sp);
        }
        asm volatile("s_waitcnt lgkmcnt(0)" ::: "memory");  // reads done
    }

    // per-thread ascending top-8 of own collected keys
    unsigned md[KNN];
#pragma unroll
    for (int kk = 0; kk < KNN; ++kk) md[kk] = SENT;
    const int m = cnt < CAP ? cnt : CAP;
    for (int kk = 0; kk < m; ++kk) {
        unsigned ky = sbuf[kk * NTHREADS + t];
#pragma unroll
        for (int i = 0; i < KNN; ++i) {
            const unsigned mn = min(ky, md[i]);
            const unsigned mx = max(ky, md[i]);
            md[i] = mn; ky = mx;
        }
    }

    // in-register bitonic merge across the 8 sublanes of each query group
#pragma unroll
    for (int off = 1; off <= 4; off <<= 1) {
        unsigned bb[8], cc[8];
#pragma unroll
        for (int j = 0; j < 8; ++j)
            bb[j] = (unsigned)__shfl_xor((int)md[j], off);
#pragma unroll
        for (int j = 0; j < 8; ++j)
            cc[j] = min(md[j], bb[7 - j]);
        CEX(cc[0], cc[4]); CEX(cc[1], cc[5]);
        CEX(cc[2], cc[6]); CEX(cc[3], cc[7]);
        CEX(cc[0], cc[2]); CEX(cc[1], cc[3]);
        CEX(cc[4], cc[6]); CEX(cc[5], cc[7]);
        CEX(cc[0], cc[1]); CEX(cc[2], cc[3]);
        CEX(cc[4], cc[5]); CEX(cc[6], cc[7]);
#pragma unroll
        for (int j = 0; j < 8; ++j) md[j] = cc[j];
    }

    // inline epilogue: lane (Q,k) resolves neighbor k of query Q, then
    // gathers its own (query,neighbor) mask-row pair directly (no LDS).
    int nb;
    {
        const unsigned ky = md[k];
        if (ky >= SENT) {
            nb = qi;  // unfilled -> self (contributes 0, matches ref)
        } else {
            const int sp = (int)(ky & 0x1FFFu);
            const float4 cc2 = csb[sp];
            const float dx = cc2.x - qx;
            const float dy = cc2.y - qy;
            const float dz = cc2.z - qz;
            const float d2 = fmaf(dx, dx, fmaf(dy, dy, dz * dz));
            // reference: idx = where(sqrt(d2) > 0.1, self_idx, idx)
            nb = (sqrtf(d2) > 0.1f) ? qi : sidx[b * NPTS + sp];
        }
    }

    // loss gather: thread (Q,k) does its full 16-ch row pair
    const float* mrow = mask + ((size_t)b * NPTS + qi) * KS;
    const float* nrow = mask + ((size_t)b * NPTS + nb) * KS;
    float acc = 0.0f;
#pragma unroll
    for (int c = 0; c < KS; c += 4) {
        const float4 a = *(const float4*)(mrow + c);
        const float4 v = *(const float4*)(nrow + c);
        acc += fabsf(a.x - v.x) + fabsf(a.y - v.y) +
               fabsf(a.z - v.z) + fabsf(a.w - v.w);
    }

    // block reduction: wave shuffle -> LDS -> one atomic per block
#pragma unroll
    for (int off = 32; off > 0; off >>= 1) acc += __shfl_down(acc, off);
    if ((t & 63) == 0) red[s] = acc;
    __syncthreads();
    if (t == 0) {
        float sum = 0.0f;
#pragma unroll
        for (int i = 0; i < NWAVE; ++i) sum += red[i];
        atomicAdd(out, sum * (1.0f / (BATCH * NPTS * KNN)));
    }
}

extern "C" void kernel_launch(void* const* d_in, const int* in_sizes, int n_in,
                              void* d_out, int out_size, void* d_ws, size_t ws_size,
                              hipStream_t stream) {
    const float* pc   = (const float*)d_in[0];  // (2, 8192, 3)
    const float* mask = (const float*)d_in[1];  // (2, 8192, 16)
    float* out = (float*)d_out;                 // scalar, poisoned 0xAA each call

    // workspace layout (336 KB used)
    float4* cs     = (float4*)d_ws;                              // 256 KB
    int*    sidx   = (int*)((char*)d_ws + 262144);               //  64 KB
    int*    cstart = (int*)((char*)d_ws + 327680);               //   8 KB

    hipLaunchKernelGGL(build_kernel, dim3(16), dim3(1024), 0, stream,
                       pc, cs, sidx, cstart, out);
    hipLaunchKernelGGL(knn_loss_kernel, dim3(NBLK), dim3(512), 0, stream,
                       cs, sidx, cstart, mask, out);
}

// Round 16
// 71.589 us; speedup vs baseline: 1.0023x; 1.0023x over previous
//
#include <hip/hip_runtime.h>

// Problem constants (fixed by setup_inputs)
#define BATCH 2
#define NPTS  8192
#define KS    16
#define KNN   8
#define R2LOOSE 0.0101f      // loose prefilter ball; exact radius test at end
#define KEYMASK 0xFFFFE000u  // high 19 bits of d2; low 13 bits = sorted pos
#define NCELL   1000         // 10x10x10 grid, cell size 0.1 (= RADIUS)
#define CSTRIDE 1024         // padded per-batch cell-array stride

// Main kernel geometry (R7/R14 best-measured: 8 queries/wave, 8 sublanes)
#define QB       64                 // queries per block
#define NWAVE    8                  // waves per block (512 threads)
#define NTHREADS 512
#define CAP      32                 // collect capacity per thread
#define SLAB     256                // per-wave staged candidates per chunk
#define NBLK     (BATCH * NPTS / QB)   // 256 blocks

__device__ __forceinline__ int cell_of(float x, float y, float z) {
    int cx = (int)(x * 10.0f); cx = cx > 9 ? 9 : cx;
    int cy = (int)(y * 10.0f); cy = cy > 9 ? 9 : cy;
    int cz = (int)(z * 10.0f); cz = cz > 9 ? 9 : cz;
    return (cx * 10 + cy) * 10 + cz;
}

// ---- single build node (R0 version, measured fastest; ~6us by R6 attrib).
// R15's dwordx3 preload was null/slightly worse -> reverted to scalar loads.
__global__ __launch_bounds__(1024) void build_kernel(
    const float* __restrict__ pc,
    float4* __restrict__ cs, int* __restrict__ sidx,
    int* __restrict__ cstart, float* __restrict__ out)
{
    __shared__ int h[1024];
    __shared__ int wsum[16];
    const int blk = blockIdx.x, t = threadIdx.x;
    const int b = blk >> 3, seg = blk & 7;     // batch, own segment
    const int lane = t & 63, w = t >> 6;

    h[t] = 0;
    if (blk == 0 && t == 0) out[0] = 0.0f;     // runs before main in-stream

    const float* p = pc + (size_t)b * NPTS * 3;
    float X[8], Y[8], Z[8]; int CC[8];
#pragma unroll
    for (int j = 0; j < 8; ++j) {
        const int i = j * 1024 + t;
        X[j] = p[3 * i]; Y[j] = p[3 * i + 1]; Z[j] = p[3 * i + 2];
        CC[j] = cell_of(X[j], Y[j], Z[j]);
    }
    __syncthreads();   // h zeroed, all loads issued

    int myold = 0;
#pragma unroll
    for (int j = 0; j < 8; ++j) {              // segment-ordered adds
        const int old = atomicAdd(&h[CC[j]], 1);
        if (j == seg) myold = old;             // bel + intra-seg rank
        __syncthreads();
    }

    const int sum = h[t];
    int inc = sum;
#pragma unroll
    for (int off = 1; off < 64; off <<= 1) {
        const int v = __shfl_up(inc, off);
        if (lane >= off) inc += v;
    }
    if (lane == 63) wsum[w] = inc;
    __syncthreads();
    if (w == 0) {
        const int v = (lane < 16) ? wsum[lane] : 0;
        int iv = v;
#pragma unroll
        for (int off = 1; off < 16; off <<= 1) {
            const int u = __shfl_up(iv, off);
            if (lane >= off) iv += u;
        }
        if (lane < 16) wsum[lane] = iv - v;    // exclusive wave offsets
    }
    __syncthreads();
    const int excl = inc - sum + wsum[w];      // per-batch exclusive prefix
    if (seg == 0) cstart[b * CSTRIDE + t] = excl;   // cells>=1000 -> 8192
    __syncthreads();
    h[t] = excl;                               // per-cell start, reusable
    __syncthreads();

    float mx = X[0], my_ = Y[0], mz = Z[0]; int mc = CC[0];
#pragma unroll
    for (int j = 1; j < 8; ++j)
        if (seg == j) { mx = X[j]; my_ = Y[j]; mz = Z[j]; mc = CC[j]; }

    const int pos = h[mc] + myold;
    const float sq = fmaf(mz, mz, fmaf(my_, my_, mx * mx));
    cs[b * NPTS + pos]   = make_float4(mx, my_, mz, -0.5f * sq);
    sidx[b * NPTS + pos] = seg * 1024 + t;     // orig within-batch index
}

// ---- fused knn + loss (R14-exact: best-measured, 70.77us) ------------------
// Structure (R7+R14): wave s owns queries [s*8,s*8+8), lane = qsub*8+k.
// Per-wave 9 covering lex intervals; chunked per-wave LDS slab staging
// (wave-local fences only); per-thread top-8; in-register bitonic 8-way
// merge; inline epilogue (no fidx/qid LDS roundtrip -- the (Q,k) thread
// already holds its own output slot).
#define CEX(a, b) { const unsigned mn_ = min(a, b), mx_ = max(a, b); \
                    a = mn_; b = mx_; }

__global__ __launch_bounds__(512) void knn_loss_kernel(
    const float4* __restrict__ cs,     // cell-sorted (x,y,z,-0.5|c|^2)
    const int*    __restrict__ sidx,   // sorted pos -> orig idx
    const int*    __restrict__ cstart, // per-batch cell starts (padded 1024)
    const float*  __restrict__ mask,   // (B, N, KS) in ORIGINAL order
    float* __restrict__ out)
{
    __shared__ float4   stg4[NWAVE][SLAB];     // 32 KB per-wave slabs
    __shared__ int      stgi[NWAVE][SLAB];     //  8 KB their sorted positions
    __shared__ unsigned sbuf[CAP * NTHREADS];  // 64 KB collect buffer
    __shared__ float    red[NWAVE];

    const int t = threadIdx.x;
    const int l = t & 63;
    const int k = l & 7;          // candidate sublane 0..7
    const int s = t >> 6;         // wave id 0..7
    const int su = __builtin_amdgcn_readfirstlane(s);
    const int Q = (t >> 3) & 63;  // query slot 0..63 (= s*8 + qsub)
    const int blk = blockIdx.x;
    const int b  = blk >> 7;
    const int q0 = (blk & 127) * QB;
    const int qpos = q0 + Q;

    const float4* csb = cs + b * NPTS;
    const float4 qc = csb[qpos];
    const int    qi = sidx[b * NPTS + qpos];

    const float qx = qc.x, qy = qc.y, qz = qc.z;
    const float qs = -2.0f * qc.w;                 // exact (power of 2)
    const float negthr = (qs - R2LOOSE) * 0.5f;    // pass iff tt >= negthr
    const unsigned SENT = (__float_as_uint(R2LOOSE) & KEYMASK) | 0x1FFFu;

    // wave's 8-query lex-cell run (8 copies of each query in the wave)
    int lex = cell_of(qx, qy, qz);
    int cmn = lex, cmx = lex;
#pragma unroll
    for (int off = 32; off; off >>= 1) {
        cmn = min(cmn, __shfl_xor(cmn, off));
        cmx = max(cmx, __shfl_xor(cmx, off));
    }
    const int cfirst = __builtin_amdgcn_readfirstlane(cmn);
    const int clast  = __builtin_amdgcn_readfirstlane(cmx);

    // 9 disjoint covering intervals (chained dedup; R7-verified scheme)
    const int* csp = cstart + b * CSTRIDE;
    int P[9], cum[9];
    int run = 0, Cw = 0;
    const int offs[9] = {-110, -100, -90, -10, 0, 10, 90, 100, 110};
#pragma unroll
    for (int i = 0; i < 9; ++i) {
        int lo = cfirst + offs[i] - 1;
        int hp = clast + offs[i] + 2;            // exclusive
        lo = min(max(lo, 0), 1000);
        hp = min(max(hp, 0), 1000);
        lo = max(lo, run);
        hp = max(hp, lo);
        run = hp;
        const int p = csp[lo], e = csp[hp];
        P[i] = p; cum[i] = Cw; Cw += e - p;
    }

    // append-only collect, branchless
    int cnt = 0;
    auto EVAL = [&](const float4& c, int spos) {
        const float tt = fmaf(c.x, qx, fmaf(c.y, qy, fmaf(c.z, qz, c.w)));
        const float d2 = fmaxf(fmaf(-2.0f, tt, qs), 0.0f);
        const unsigned key =
            (__float_as_uint(d2) & KEYMASK) | (unsigned)spos;
        const int slot = cnt < (CAP - 1) ? cnt : (CAP - 1);
        sbuf[slot * NTHREADS + t] = key;
        cnt += (tt >= negthr) ? 1 : 0;
    };

    // chunked per-wave stage + eval (no block barriers; wave-local fence)
    for (int fb = 0; fb < Cw; fb += SLAB) {
        const int n = min(SLAB, Cw - fb);        // wave-uniform
        for (int f = l; f < n; f += 64) {        // 64-wide coalesced stage
            const int g = fb + f;
            int sp = P[0] + g;
#pragma unroll
            for (int i = 1; i < 9; ++i)
                sp = (g >= cum[i]) ? P[i] + (g - cum[i]) : sp;
            stg4[su][f] = csb[sp];
            stgi[su][f] = sp;
        }
        asm volatile("s_waitcnt lgkmcnt(0)" ::: "memory");  // stage visible

        for (int j = k; j < n; j += 8) {         // sublane-strided eval
            const float4 c = stg4[su][j];
            const int   sp = stgi[su][j];
            EVAL(c, sp);
        }
        asm volatile("s_waitcnt lgkmcnt(0)" ::: "memory");  // reads done
    }

    // per-thread ascending top-8 of own collected keys
    unsigned md[KNN];
#pragma unroll
    for (int kk = 0; kk < KNN; ++kk) md[kk] = SENT;
    const int m = cnt < CAP ? cnt : CAP;
    for (int kk = 0; kk < m; ++kk) {
        unsigned ky = sbuf[kk * NTHREADS + t];
#pragma unroll
        for (int i = 0; i < KNN; ++i) {
            const unsigned mn = min(ky, md[i]);
            const unsigned mx = max(ky, md[i]);
            md[i] = mn; ky = mx;
        }
    }

    // in-register bitonic merge across the 8 sublanes of each query group
#pragma unroll
    for (int off = 1; off <= 4; off <<= 1) {
        unsigned bb[8], cc[8];
#pragma unroll
        for (int j = 0; j < 8; ++j)
            bb[j] = (unsigned)__shfl_xor((int)md[j], off);
#pragma unroll
        for (int j = 0; j < 8; ++j)
            cc[j] = min(md[j], bb[7 - j]);
        CEX(cc[0], cc[4]); CEX(cc[1], cc[5]);
        CEX(cc[2], cc[6]); CEX(cc[3], cc[7]);
        CEX(cc[0], cc[2]); CEX(cc[1], cc[3]);
        CEX(cc[4], cc[6]); CEX(cc[5], cc[7]);
        CEX(cc[0], cc[1]); CEX(cc[2], cc[3]);
        CEX(cc[4], cc[5]); CEX(cc[6], cc[7]);
#pragma unroll
        for (int j = 0; j < 8; ++j) md[j] = cc[j];
    }

    // inline epilogue: lane (Q,k) resolves neighbor k of query Q, then
    // gathers its own (query,neighbor) mask-row pair directly (no LDS).
    int nb;
    {
        const unsigned ky = md[k];
        if (ky >= SENT) {
            nb = qi;  // unfilled -> self (contributes 0, matches ref)
        } else {
            const int sp = (int)(ky & 0x1FFFu);
            const float4 cc2 = csb[sp];
            const float dx = cc2.x - qx;
            const float dy = cc2.y - qy;
            const float dz = cc2.z - qz;
            const float d2 = fmaf(dx, dx, fmaf(dy, dy, dz * dz));
            // reference: idx = where(sqrt(d2) > 0.1, self_idx, idx)
            nb = (sqrtf(d2) > 0.1f) ? qi : sidx[b * NPTS + sp];
        }
    }

    // loss gather: thread (Q,k) does its full 16-ch row pair
    const float* mrow = mask + ((size_t)b * NPTS + qi) * KS;
    const float* nrow = mask + ((size_t)b * NPTS + nb) * KS;
    float acc = 0.0f;
#pragma unroll
    for (int c = 0; c < KS; c += 4) {
        const float4 a = *(const float4*)(mrow + c);
        const float4 v = *(const float4*)(nrow + c);
        acc += fabsf(a.x - v.x) + fabsf(a.y - v.y) +
               fabsf(a.z - v.z) + fabsf(a.w - v.w);
    }

    // block reduction: wave shuffle -> LDS -> one atomic per block
#pragma unroll
    for (int off = 32; off > 0; off >>= 1) acc += __shfl_down(acc, off);
    if ((t & 63) == 0) red[s] = acc;
    __syncthreads();
    if (t == 0) {
        float sum = 0.0f;
#pragma unroll
        for (int i = 0; i < NWAVE; ++i) sum += red[i];
        atomicAdd(out, sum * (1.0f / (BATCH * NPTS * KNN)));
    }
}

extern "C" void kernel_launch(void* const* d_in, const int* in_sizes, int n_in,
                              void* d_out, int out_size, void* d_ws, size_t ws_size,
                              hipStream_t stream) {
    const float* pc   = (const float*)d_in[0];  // (2, 8192, 3)
    const float* mask = (const float*)d_in[1];  // (2, 8192, 16)
    float* out = (float*)d_out;                 // scalar, poisoned 0xAA each call

    // workspace layout (336 KB used)
    float4* cs     = (float4*)d_ws;                              // 256 KB
    int*    sidx   = (int*)((char*)d_ws + 262144);               //  64 KB
    int*    cstart = (int*)((char*)d_ws + 327680);               //   8 KB

    hipLaunchKernelGGL(build_kernel, dim3(16), dim3(1024), 0, stream,
                       pc, cs, sidx, cstart, out);
    hipLaunchKernelGGL(knn_loss_kernel, dim3(NBLK), dim3(512), 0, stream,
                       cs, sidx, cstart, mask, out);
}